// Round 1
// baseline (589.689 us; speedup 1.0000x reference)
//
#include <hip/hip_runtime.h>
#include <hip/hip_bf16.h>

typedef unsigned short ushort_t;
typedef unsigned int uint32;
typedef __attribute__((ext_vector_type(4))) float f32x4;
typedef __attribute__((ext_vector_type(8))) short s16x8;

#define D_DIM 1024
#define V_DIM 1024
#define U_DIM 64
#define T_DIM 256

#define BM 128
#define BN 128
#define BK 64

// round-to-nearest-even f32 -> bf16
__device__ __forceinline__ ushort_t f2bf(float f) {
  uint32 u = __builtin_bit_cast(uint32, f);
  u += 0x7fffu + ((u >> 16) & 1u);
  return (ushort_t)(u >> 16);
}
__device__ __forceinline__ uint32 pack2(float a, float b) {
  return (uint32)f2bf(a) | ((uint32)f2bf(b) << 16);
}

// Convert W (V x D f32) to bf16 row-major in workspace (2 MB).
__global__ void wconv_kernel(const float* __restrict__ W, ushort_t* __restrict__ Wb) {
  int i = (blockIdx.x * 256 + threadIdx.x) * 8;
  f32x4 a = *(const f32x4*)(W + i);
  f32x4 b = *(const f32x4*)(W + i + 4);
  uint4 w;
  w.x = pack2(a[0], a[1]);
  w.y = pack2(a[2], a[3]);
  w.z = pack2(b[0], b[1]);
  w.w = pack2(b[2], b[3]);
  *(uint4*)(Wb + i) = w;
}

// Tuple outputs 1,2: lengths as float at the tail of d_out.
__global__ void lens_kernel(const int* __restrict__ sl, const int* __restrict__ tl,
                            float* __restrict__ out, int out_size) {
  int t = threadIdx.x;
  if (t < 4) out[out_size - 8 + t] = (float)sl[t];
  else if (t < 8) out[out_size - 8 + t] = (float)tl[t - 4];
}

// Fused joiner GEMM: C[m, v] = sum_d relu(src[bt(m),d] + tgt[bu(m),d]) * W[v,d] + bias[v]
// m = ((b*T + t)*U + u); BM=128 rows = 2 src rows x 64 tgt rows.
__global__ __launch_bounds__(256) void joiner_gemm(
    const float* __restrict__ src, const float* __restrict__ tgt,
    const ushort_t* __restrict__ Wb, const float* __restrict__ bias,
    float* __restrict__ out) {
  // Swizzled tiles: LDS (row, chunk16B c) holds logical chunk (c ^ (row&7)).
  __shared__ ushort_t As[BM * BK];  // 16 KB
  __shared__ ushort_t Bs[BN * BK];  // 16 KB

  const int tid = threadIdx.x;
  const int lane = tid & 63;
  const int wid = tid >> 6;       // 4 waves, 2x2 grid of 64x64
  const int wr = wid >> 1;
  const int wc = wid & 1;

  // XCD-aware bijective swizzle: nwg = 4096 = 8 * 512
  const int bid = blockIdx.x;
  const int work = (bid & 7) * 512 + (bid >> 3);
  const int m0 = (work >> 3) * BM;   // 512 m-tiles
  const int n0 = (work & 7) * BN;    // 8 n-tiles

  // ---- A staging precompute: thread -> (row r, half of K-tile) ----
  const int r = tid & 127;
  const int half = tid >> 7;
  const int mrow = m0 + r;
  const int bt = mrow >> 6;        // b*T + t
  const int uu = mrow & 63;        // u
  const int bI = bt >> 8;          // b
  const float* srow = src + (size_t)bt * D_DIM + half * 32;
  const float* trow = tgt + (size_t)(bI * U_DIM + uu) * D_DIM + half * 32;
  int aw[4];  // swizzled LDS write indices (ushort units), constant over K
#pragma unroll
  for (int i = 0; i < 4; ++i) {
    int c16 = half * 4 + i;
    aw[i] = r * 64 + ((c16 ^ (r & 7)) << 3);
  }

  // ---- B staging precompute: pre-swizzled per-lane global source ----
  // wave 'wid' stages rows [wid*32, wid*32+32) in 4 global_load_lds
  const int rB = wid * 32 + (lane >> 3);
  const int cg = (lane & 7) ^ (lane >> 3);  // rowB&7 == lane>>3
  const ushort_t* bsrc = Wb + (size_t)(n0 + rB) * D_DIM + cg * 8;
  ushort_t* bdst = Bs + wid * 4 * 512;

  // ---- MFMA fragment addressing ----
  int rowA[4], rowB[4];
#pragma unroll
  for (int i = 0; i < 4; ++i) {
    rowA[i] = wr * 64 + i * 16 + (lane & 15);
    rowB[i] = wc * 64 + i * 16 + (lane & 15);
  }
  const int kq = lane >> 4;

  f32x4 acc[4][4];
#pragma unroll
  for (int i = 0; i < 4; ++i)
#pragma unroll
    for (int j = 0; j < 4; ++j) acc[i][j] = (f32x4){0.f, 0.f, 0.f, 0.f};

  for (int k0 = 0; k0 < D_DIM; k0 += BK) {
    // B tile: async global->LDS, source addresses pre-swizzled so linear
    // LDS dest lands in swizzled order (m173 pattern).
#pragma unroll
    for (int i = 0; i < 4; ++i) {
      __builtin_amdgcn_global_load_lds(
          (const __attribute__((address_space(1))) uint32*)(const void*)(bsrc + (size_t)i * 8 * D_DIM + k0),
          (__attribute__((address_space(3))) uint32*)(void*)(bdst + i * 512),
          16, 0, 0);
    }
    // A tile: fused relu(src+tgt) -> bf16, swizzled ds_write_b128
#pragma unroll
    for (int i = 0; i < 4; ++i) {
      f32x4 s0 = *(const f32x4*)(srow + k0 + i * 8);
      f32x4 s1 = *(const f32x4*)(srow + k0 + i * 8 + 4);
      f32x4 t0 = *(const f32x4*)(trow + k0 + i * 8);
      f32x4 t1 = *(const f32x4*)(trow + k0 + i * 8 + 4);
      uint4 w;
      w.x = pack2(fmaxf(s0[0] + t0[0], 0.f), fmaxf(s0[1] + t0[1], 0.f));
      w.y = pack2(fmaxf(s0[2] + t0[2], 0.f), fmaxf(s0[3] + t0[3], 0.f));
      w.z = pack2(fmaxf(s1[0] + t1[0], 0.f), fmaxf(s1[1] + t1[1], 0.f));
      w.w = pack2(fmaxf(s1[2] + t1[2], 0.f), fmaxf(s1[3] + t1[3], 0.f));
      *(uint4*)(As + aw[i]) = w;
    }
    __syncthreads();

#pragma unroll
    for (int kk = 0; kk < 2; ++kk) {
      const int c16 = kk * 4 + kq;
      s16x8 af[4], bf[4];
#pragma unroll
      for (int i = 0; i < 4; ++i) {
        af[i] = *(const s16x8*)(As + rowA[i] * 64 + ((c16 ^ (rowA[i] & 7)) << 3));
        bf[i] = *(const s16x8*)(Bs + rowB[i] * 64 + ((c16 ^ (rowB[i] & 7)) << 3));
      }
#pragma unroll
      for (int mi = 0; mi < 4; ++mi)
#pragma unroll
        for (int ni = 0; ni < 4; ++ni)
          acc[mi][ni] = __builtin_amdgcn_mfma_f32_16x16x32_bf16(af[mi], bf[ni], acc[mi][ni], 0, 0, 0);
    }
    __syncthreads();
  }

  // ---- epilogue: C/D layout col=lane&15, row=(lane>>4)*4+j ----
  const int col0 = n0 + wc * 64 + (lane & 15);
  const int row0 = m0 + wr * 64 + ((lane >> 4) << 2);
#pragma unroll
  for (int ni = 0; ni < 4; ++ni) {
    float bv = bias[col0 + ni * 16];
#pragma unroll
    for (int mi = 0; mi < 4; ++mi) {
      size_t base = (size_t)(row0 + mi * 16) * V_DIM + (col0 + ni * 16);
#pragma unroll
      for (int j = 0; j < 4; ++j)
        out[base + (size_t)j * V_DIM] = acc[mi][ni][j] + bv;
    }
  }
}

extern "C" void kernel_launch(void* const* d_in, const int* in_sizes, int n_in,
                              void* d_out, int out_size, void* d_ws, size_t ws_size,
                              hipStream_t stream) {
  const float* src  = (const float*)d_in[0];
  const int*   slen = (const int*)d_in[1];
  const float* tgt  = (const float*)d_in[2];
  const int*   tlen = (const int*)d_in[3];
  const float* W    = (const float*)d_in[4];
  const float* bias = (const float*)d_in[5];
  float* out = (float*)d_out;
  ushort_t* Wb = (ushort_t*)d_ws;  // 2 MB bf16 copy of W

  wconv_kernel<<<dim3(512), dim3(256), 0, stream>>>(W, Wb);
  lens_kernel<<<dim3(1), dim3(64), 0, stream>>>(slen, tlen, out, out_size);
  joiner_gemm<<<dim3(4096), dim3(256), 0, stream>>>(src, tgt, Wb, bias, out);
}

// Round 2
// 445.533 us; speedup vs baseline: 1.3236x; 1.3236x over previous
//
#include <hip/hip_runtime.h>
#include <hip/hip_bf16.h>
#include <hip/hip_fp16.h>

typedef unsigned short ushort_t;
typedef unsigned int uint32;
typedef __attribute__((ext_vector_type(4))) float f32x4;
typedef __attribute__((ext_vector_type(8))) _Float16 f16x8;
typedef __attribute__((ext_vector_type(2))) _Float16 f16x2;

#define D_DIM 1024
#define V_DIM 1024
#define U_DIM 64
#define T_DIM 256

#define BM 128
#define BN 128
#define BK 64

// f32 -> fp16 array conversion (RNE), 8 elems/thread
__global__ void conv_kernel(const float* __restrict__ in, _Float16* __restrict__ out, int n) {
  int i = (blockIdx.x * 256 + threadIdx.x) * 8;
  if (i >= n) return;
  f32x4 a = *(const f32x4*)(in + i);
  f32x4 b = *(const f32x4*)(in + i + 4);
  f16x8 v;
#pragma unroll
  for (int j = 0; j < 4; ++j) { v[j] = (_Float16)a[j]; v[4 + j] = (_Float16)b[j]; }
  *(f16x8*)(out + i) = v;
}

// Tuple outputs 1,2: lengths as float at the tail of d_out.
__global__ void lens_kernel(const int* __restrict__ sl, const int* __restrict__ tl,
                            float* __restrict__ out, int out_size) {
  int t = threadIdx.x;
  if (t < 4) out[out_size - 8 + t] = (float)sl[t];
  else if (t < 8) out[out_size - 8 + t] = (float)tl[t - 4];
}

// Fused joiner GEMM: C[m, v] = sum_d relu(src[bt(m),d] + tgt[bu(m),d]) * W[v,d] + bias[v]
// PREH=true: src/tgt pre-converted to fp16 (packed add/max). false: f32 on-the-fly.
template <bool PREH>
__global__ __launch_bounds__(256) void joiner_gemm(
    const void* __restrict__ srcv, const void* __restrict__ tgtv,
    const _Float16* __restrict__ Wh, const float* __restrict__ bias,
    float* __restrict__ out) {
  __shared__ _Float16 As[BM * BK];       // 16 KB
  __shared__ _Float16 Bs[2][BN * BK];    // 32 KB (double-buffered)

  const int tid = threadIdx.x;
  const int lane = tid & 63;
  const int wid = tid >> 6;  // 4 waves, 2x2 grid of 64x64
  const int wr = wid >> 1;
  const int wc = wid & 1;

  // XCD-aware bijective swizzle: nwg = 4096 = 8 * 512
  const int bid = blockIdx.x;
  const int work = (bid & 7) * 512 + (bid >> 3);
  const int m0 = (work >> 3) * BM;
  const int n0 = (work & 7) * BN;

  // ---- A staging: thread -> (row r, half of K-tile), 32 elems/thread ----
  const int r = tid & 127;
  const int half = tid >> 7;
  const int mrow = m0 + r;
  const int bt = mrow >> 6;  // b*T + t
  const int uu = mrow & 63;  // u
  const int bI = bt >> 8;    // b
  const _Float16* srowh = nullptr; const _Float16* trowh = nullptr;
  const float* srowf = nullptr; const float* trowf = nullptr;
  if constexpr (PREH) {
    srowh = (const _Float16*)srcv + (size_t)bt * D_DIM + half * 32;
    trowh = (const _Float16*)tgtv + (size_t)(bI * U_DIM + uu) * D_DIM + half * 32;
  } else {
    srowf = (const float*)srcv + (size_t)bt * D_DIM + half * 32;
    trowf = (const float*)tgtv + (size_t)(bI * U_DIM + uu) * D_DIM + half * 32;
  }
  int aw[4];  // swizzled LDS write indices (elem units)
#pragma unroll
  for (int i = 0; i < 4; ++i) {
    int c16 = half * 4 + i;
    aw[i] = r * 64 + ((c16 ^ (r & 7)) << 3);
  }

  // ---- B staging: pre-swizzled per-lane global source (m173 pattern) ----
  const int rB = wid * 32 + (lane >> 3);
  const int cg = (lane & 7) ^ (lane >> 3);
  const _Float16* bsrc = Wh + (size_t)(n0 + rB) * D_DIM + cg * 8;

  // ---- MFMA fragment addressing ----
  int rowA[4], rowB[4];
#pragma unroll
  for (int i = 0; i < 4; ++i) {
    rowA[i] = wr * 64 + i * 16 + (lane & 15);
    rowB[i] = wc * 64 + i * 16 + (lane & 15);
  }
  const int kq = lane >> 4;

  f32x4 acc[4][4];
#pragma unroll
  for (int i = 0; i < 4; ++i)
#pragma unroll
    for (int j = 0; j < 4; ++j) acc[i][j] = (f32x4){0.f, 0.f, 0.f, 0.f};

  // A-prefetch registers
  f16x8 sA[4], tA[4];
  f32x4 sF[8], tF[8];

  auto LOADA = [&](int k) {
    if constexpr (PREH) {
#pragma unroll
      for (int i = 0; i < 4; ++i) {
        sA[i] = *(const f16x8*)(srowh + k + i * 8);
        tA[i] = *(const f16x8*)(trowh + k + i * 8);
      }
    } else {
#pragma unroll
      for (int i = 0; i < 8; ++i) {
        sF[i] = *(const f32x4*)(srowf + k + i * 4);
        tF[i] = *(const f32x4*)(trowf + k + i * 4);
      }
    }
  };

  auto ISSUEB = [&](int k, int buf) {
    _Float16* bd = &Bs[buf][wid * 4 * 512];
#pragma unroll
    for (int i = 0; i < 4; ++i) {
      __builtin_amdgcn_global_load_lds(
          (const __attribute__((address_space(1))) uint32*)(const void*)(bsrc + (size_t)i * 8 * D_DIM + k),
          (__attribute__((address_space(3))) uint32*)(void*)(bd + i * 512),
          16, 0, 0);
    }
  };

  auto STAGEA = [&]() {
    if constexpr (PREH) {
      const f16x8 z = {0, 0, 0, 0, 0, 0, 0, 0};
#pragma unroll
      for (int i = 0; i < 4; ++i) {
        f16x8 v = sA[i] + tA[i];
        v = __builtin_elementwise_max(v, z);
        *(f16x8*)(As + aw[i]) = v;
      }
    } else {
#pragma unroll
      for (int i = 0; i < 4; ++i) {
        f32x4 a0 = sF[2 * i], a1 = sF[2 * i + 1];
        f32x4 t0 = tF[2 * i], t1 = tF[2 * i + 1];
        f16x8 v;
#pragma unroll
        for (int j = 0; j < 4; ++j) {
          v[j] = (_Float16)fmaxf(a0[j] + t0[j], 0.f);
          v[4 + j] = (_Float16)fmaxf(a1[j] + t1[j], 0.f);
        }
        *(f16x8*)(As + aw[i]) = v;
      }
    }
  };

  LOADA(0);
  ISSUEB(0, 0);
  int cur = 0;

  for (int k0 = 0; k0 < D_DIM; k0 += BK) {
    STAGEA();
    __syncthreads();  // drains B gl_lds (issued last compute region) + A ds_writes

    const bool more = (k0 + BK) < D_DIM;
#pragma unroll
    for (int kk = 0; kk < 2; ++kk) {
      const int c16 = kk * 4 + kq;
      f16x8 af[4], bf[4];
#pragma unroll
      for (int i = 0; i < 4; ++i) {
        af[i] = *(const f16x8*)(As + rowA[i] * 64 + ((c16 ^ (rowA[i] & 7)) << 3));
        bf[i] = *(const f16x8*)(&Bs[cur][0] + rowB[i] * 64 + ((c16 ^ (rowB[i] & 7)) << 3));
      }
      if (kk == 0 && more) {
        LOADA(k0 + BK);        // next A inputs: latency hidden under MFMA cluster
        ISSUEB(k0 + BK, cur ^ 1);  // next B tile into other buffer
      }
#pragma unroll
      for (int mi = 0; mi < 4; ++mi)
#pragma unroll
        for (int ni = 0; ni < 4; ++ni)
          acc[mi][ni] = __builtin_amdgcn_mfma_f32_16x16x32_f16(af[mi], bf[ni], acc[mi][ni], 0, 0, 0);
    }
    __syncthreads();
    cur ^= 1;
  }

  // ---- epilogue: C/D layout col=lane&15, row=(lane>>4)*4+j ----
  const int col0 = n0 + wc * 64 + (lane & 15);
  const int row0 = m0 + wr * 64 + ((lane >> 4) << 2);
#pragma unroll
  for (int ni = 0; ni < 4; ++ni) {
    float bv = bias[col0 + ni * 16];
#pragma unroll
    for (int mi = 0; mi < 4; ++mi) {
      size_t base = (size_t)(row0 + mi * 16) * V_DIM + (col0 + ni * 16);
#pragma unroll
      for (int j = 0; j < 4; ++j)
        out[base + (size_t)j * V_DIM] = acc[mi][ni][j] + bv;
    }
  }
}

extern "C" void kernel_launch(void* const* d_in, const int* in_sizes, int n_in,
                              void* d_out, int out_size, void* d_ws, size_t ws_size,
                              hipStream_t stream) {
  const float* src  = (const float*)d_in[0];
  const int*   slen = (const int*)d_in[1];
  const float* tgt  = (const float*)d_in[2];
  const int*   tlen = (const int*)d_in[3];
  const float* W    = (const float*)d_in[4];
  const float* bias = (const float*)d_in[5];
  float* out = (float*)d_out;

  _Float16* Wh   = (_Float16*)d_ws;            // 2 MB
  _Float16* srch = Wh + (size_t)V_DIM * D_DIM; // +2 MB
  _Float16* tgth = srch + (size_t)4 * T_DIM * D_DIM;  // +0.5 MB

  const int nW = V_DIM * D_DIM;          // 1,048,576
  const int nS = 4 * T_DIM * D_DIM;      // 1,048,576
  const int nT = 4 * U_DIM * D_DIM;      // 262,144
  const bool pre = ws_size >= ((size_t)9 << 19);  // 4.5 MB needed

  conv_kernel<<<dim3(nW / 2048), dim3(256), 0, stream>>>(W, Wh, nW);
  if (pre) {
    conv_kernel<<<dim3(nS / 2048), dim3(256), 0, stream>>>(src, srch, nS);
    conv_kernel<<<dim3(nT / 2048), dim3(256), 0, stream>>>(tgt, tgth, nT);
  }
  lens_kernel<<<dim3(1), dim3(64), 0, stream>>>(slen, tlen, out, out_size);

  if (pre) {
    joiner_gemm<true><<<dim3(4096), dim3(256), 0, stream>>>(srch, tgth, Wh, bias, out);
  } else {
    joiner_gemm<false><<<dim3(4096), dim3(256), 0, stream>>>(src, tgt, Wh, bias, out);
  }
}